// Round 1
// baseline (6884.087 us; speedup 1.0000x reference)
//
#include <hip/hip_runtime.h>
#include <hip/hip_bf16.h>

typedef __hip_bfloat16 bf16;

#define N_TOK (4 * 65536)   // 262144 tokens total
#define IMG 256
#define CD 180

__device__ __forceinline__ float wave_reduce_add(float v) {
#pragma unroll
  for (int m = 32; m > 0; m >>= 1) v += __shfl_xor(v, m, 64);
  return v;
}

__device__ __forceinline__ float gelu_f(float v) {
  return 0.5f * v * (1.f + erff(v * 0.70710678118654752f));
}

__device__ __forceinline__ void fma16(float* acc, float w, const float* p) {
  const float4* v4 = (const float4*)p;
  float4 a = v4[0], b = v4[1], c = v4[2], d = v4[3];
  acc[0] += w * a.x;  acc[1] += w * a.y;  acc[2] += w * a.z;  acc[3] += w * a.w;
  acc[4] += w * b.x;  acc[5] += w * b.y;  acc[6] += w * b.z;  acc[7] += w * b.w;
  acc[8] += w * c.x;  acc[9] += w * c.y;  acc[10] += w * c.z; acc[11] += w * c.w;
  acc[12] += w * d.x; acc[13] += w * d.y; acc[14] += w * d.z; acc[15] += w * d.w;
}

// ---------------- repack kernels (run every call; ~1.5 MB total) ----------------

__global__ void k_zero(float* __restrict__ p, int n) {
  int i = blockIdx.x * 256 + threadIdx.x;
  if (i < n) p[i] = 0.f;
}

// qkv_wt[c*540 + oo], oo = h*90 + r ; r<30:q(d) 30..59:k 60..89:v ; q rows pre-scaled
__global__ void k_repack_qkv(const float* __restrict__ w, const float* __restrict__ b,
                             float* __restrict__ wt, float* __restrict__ bt) {
  int i = blockIdx.x * 256 + threadIdx.x;
  if (i >= 540 * 180) return;
  int c = i / 540, oo = i % 540;
  int hh = oo / 90, r = oo % 90;
  int mat = r / 30, d = r % 30;
  int o = mat * 180 + hh * 30 + d;
  float s = (mat == 0) ? 0.18257418583505537f : 1.f;  // 30^-0.5
  wt[i] = w[o * 180 + c] * s;
  if (c == 0) bt[oo] = b[o] * s;
}

// projT[j*180 + c] = proj_w[c*180 + j]
__global__ void k_repack_proj(const float* __restrict__ w, float* __restrict__ wt) {
  int i = blockIdx.x * 256 + threadIdx.x;
  if (i >= 180 * 180) return;
  int j = i / 180, c = i % 180;
  wt[i] = w[c * 180 + j];
}

// fc1T[c*720 + o] = fc1_w[o*180 + c]
__global__ void k_repack_fc1(const float* __restrict__ w, float* __restrict__ wt) {
  int i = blockIdx.x * 256 + threadIdx.x;
  if (i >= 180 * 720) return;
  int c = i / 720, o = i % 720;
  wt[i] = w[o * 180 + c];
}

// fc2T[j*180 + c] = fc2_w[c*720 + j]
__global__ void k_repack_fc2(const float* __restrict__ w, float* __restrict__ wt) {
  int i = blockIdx.x * 256 + threadIdx.x;
  if (i >= 720 * 180) return;
  int j = i / 180, c = i % 180;
  wt[i] = w[c * 720 + j];
}

// w1r[(kk*180 + ci)*60 + o] = cab_w1[o][ci][ky][kx]
__global__ void k_repack_w1(const float* __restrict__ w, float* __restrict__ wt) {
  int i = blockIdx.x * 256 + threadIdx.x;
  if (i >= 9 * 180 * 60) return;
  int o = i % 60; int t = i / 60; int c = t % 180; int kk = t / 180;
  int ky = kk / 3, kx = kk % 3;
  wt[i] = w[((o * 180 + c) * 3 + ky) * 3 + kx];
}

// w2r[(kk*60 + ci)*180 + o] = cab_w2[o][ci][ky][kx]
__global__ void k_repack_w2(const float* __restrict__ w, float* __restrict__ wt) {
  int i = blockIdx.x * 256 + threadIdx.x;
  if (i >= 9 * 60 * 180) return;
  int o = i % 180; int t = i / 180; int c = t % 60; int kk = t / 60;
  int ky = kk / 3, kx = kk % 3;
  wt[i] = w[((o * 60 + c) * 3 + ky) * 3 + kx];
}

// ---------------- LN1: x -> xn (bf16) ----------------

__global__ __launch_bounds__(256) void k_ln1(const float* __restrict__ x,
                                             const float* __restrict__ gw,
                                             const float* __restrict__ bw,
                                             bf16* __restrict__ xn) {
  int wv = threadIdx.x >> 6, lane = threadIdx.x & 63;
  long row = (long)blockIdx.x * 4 + wv;
  const float* xr = x + row * 180;
  float v0 = xr[lane];
  float v1 = xr[lane + 64];
  float v2 = (lane < 52) ? xr[lane + 128] : 0.f;
  float s = wave_reduce_add(v0 + v1 + v2);
  float ss = wave_reduce_add(v0 * v0 + v1 * v1 + v2 * v2);
  float mean = s * (1.f / 180.f);
  float var = ss * (1.f / 180.f) - mean * mean;
  float rstd = rsqrtf(var + 1e-5f);
  bf16* xo = xn + row * 180;
  xo[lane] = __float2bfloat16((v0 - mean) * rstd * gw[lane] + bw[lane]);
  xo[lane + 64] = __float2bfloat16((v1 - mean) * rstd * gw[lane + 64] + bw[lane + 64]);
  if (lane < 52)
    xo[lane + 128] = __float2bfloat16((v2 - mean) * rstd * gw[lane + 128] + bw[lane + 128]);
}

// ---------------- conv1 3x3 180->60 + GELU ----------------

__global__ __launch_bounds__(256) void k_conv1(const bf16* __restrict__ xn,
                                               const float* __restrict__ w1r,
                                               const float* __restrict__ b1,
                                               bf16* __restrict__ y60) {
  __shared__ float tile[18 * 18 * 36];
  int b = blockIdx.y;
  int ty = blockIdx.x >> 4, tx = blockIdx.x & 15;
  int px = threadIdx.x & 15, py = threadIdx.x >> 4;
  float acc[60];
#pragma unroll
  for (int o = 0; o < 60; o++) acc[o] = b1[o];
  long ibase = (long)b * 65536;
  for (int cc = 0; cc < 180; cc += 36) {
    __syncthreads();
    for (int idx = threadIdx.x; idx < 18 * 18 * 36; idx += 256) {
      int c = idx % 36; int t2 = idx / 36; int col = t2 % 18; int r = t2 / 18;
      int iy = ty * 16 - 1 + r, ix = tx * 16 - 1 + col;
      float v = 0.f;
      if (iy >= 0 && iy < IMG && ix >= 0 && ix < IMG)
        v = __bfloat162float(xn[(ibase + iy * IMG + ix) * 180 + cc + c]);
      tile[idx] = v;
    }
    __syncthreads();
    for (int kk = 0; kk < 9; kk++) {
      const float* wp = w1r + (kk * 180 + cc) * 60;
      const float* tp = tile + ((py + kk / 3) * 18 + (px + kk % 3)) * 36;
      for (int c = 0; c < 36; c++) {
        float v = tp[c];
        const float* w = wp + c * 60;
#pragma unroll
        for (int o = 0; o < 60; o++) acc[o] += v * w[o];
      }
    }
  }
  long g = ibase + (ty * 16 + py) * IMG + (tx * 16 + px);
  bf16* outp = y60 + g * 60;
#pragma unroll
  for (int o = 0; o < 60; o++) outp[o] = __float2bfloat16(gelu_f(acc[o]));
}

// ---------------- conv2 3x3 60->180 ----------------

__global__ __launch_bounds__(256) void k_conv2(const bf16* __restrict__ y60,
                                               const float* __restrict__ w2r,
                                               const float* __restrict__ b2,
                                               bf16* __restrict__ y180) {
  __shared__ float tile[18 * 18 * 30];
  int b = blockIdx.z, og = blockIdx.y;  // og in {0,1}: 90 channels each
  int ty = blockIdx.x >> 4, tx = blockIdx.x & 15;
  int px = threadIdx.x & 15, py = threadIdx.x >> 4;
  float acc[90];
  const float* bb = b2 + og * 90;
#pragma unroll
  for (int j = 0; j < 90; j++) acc[j] = bb[j];
  long ibase = (long)b * 65536;
  for (int cc = 0; cc < 60; cc += 30) {
    __syncthreads();
    for (int idx = threadIdx.x; idx < 18 * 18 * 30; idx += 256) {
      int c = idx % 30; int t2 = idx / 30; int col = t2 % 18; int r = t2 / 18;
      int iy = ty * 16 - 1 + r, ix = tx * 16 - 1 + col;
      float v = 0.f;
      if (iy >= 0 && iy < IMG && ix >= 0 && ix < IMG)
        v = __bfloat162float(y60[(ibase + iy * IMG + ix) * 60 + cc + c]);
      tile[idx] = v;
    }
    __syncthreads();
    for (int kk = 0; kk < 9; kk++) {
      const float* wp = w2r + (kk * 60 + cc) * 180 + og * 90;
      const float* tp = tile + ((py + kk / 3) * 18 + (px + kk % 3)) * 30;
      for (int c = 0; c < 30; c++) {
        float v = tp[c];
        const float* w = wp + c * 180;
#pragma unroll
        for (int j = 0; j < 90; j++) acc[j] += v * w[j];
      }
    }
  }
  long g = ibase + (ty * 16 + py) * IMG + (tx * 16 + px);
  bf16* outp = y180 + g * 180 + og * 90;
#pragma unroll
  for (int j = 0; j < 90; j++) outp[j] = __float2bfloat16(acc[j]);
}

// ---------------- per-channel sums (for adaptive avg pool) ----------------

__global__ __launch_bounds__(192) void k_csum(const bf16* __restrict__ y180,
                                              float* __restrict__ cs) {
  int c = threadIdx.x;
  if (c >= 180) return;
  int b = blockIdx.y;
  long base = ((long)b * 65536 + blockIdx.x * 256) * 180;
  float s = 0.f;
  for (int p = 0; p < 256; p++) s += __bfloat162float(y180[base + p * 180 + c]);
  atomicAdd(&cs[b * 180 + c], s);
}

// ---------------- SE: mean -> 6 -> relu -> 180 -> sigmoid ----------------

__global__ __launch_bounds__(192) void k_se(const float* __restrict__ cs,
                                            const float* __restrict__ w1,
                                            const float* __restrict__ b1,
                                            const float* __restrict__ w2,
                                            const float* __restrict__ b2,
                                            float* __restrict__ a_se) {
  __shared__ float m[180];
  __shared__ float hid[6];
  int b = blockIdx.x, t = threadIdx.x;
  if (t < 180) m[t] = cs[b * 180 + t] * (1.f / 65536.f);
  __syncthreads();
  if (t < 6) {
    float s = b1[t];
    for (int c = 0; c < 180; c++) s += m[c] * w1[t * 180 + c];
    hid[t] = fmaxf(s, 0.f);
  }
  __syncthreads();
  if (t < 180) {
    float s = b2[t];
#pragma unroll
    for (int j = 0; j < 6; j++) s += hid[j] * w2[t * 6 + j];
    a_se[b * 180 + t] = 1.f / (1.f + __expf(-s));
  }
}

// ---------------- qkv GEMM: xn(262144x180) @ wt(180x540) + bt -> qkvb bf16 ----------------

__global__ __launch_bounds__(256) void k_qkv(const bf16* __restrict__ xn,
                                             const float* __restrict__ wt,
                                             const float* __restrict__ bt,
                                             bf16* __restrict__ qkvb) {
  __shared__ float xrT[180 * 16];  // [c][r]
  long row0 = (long)blockIdx.x * 16;
  for (int idx = threadIdx.x; idx < 16 * 180; idx += 256) {
    int r = idx / 180, c = idx % 180;
    xrT[c * 16 + r] = __bfloat162float(xn[(row0 + r) * 180 + c]);
  }
  __syncthreads();
  for (int o = threadIdx.x; o < 540; o += 256) {
    float acc[16];
#pragma unroll
    for (int j = 0; j < 16; j++) acc[j] = 0.f;
    const float* wp = wt + o;
    for (int c = 0; c < 180; c++) fma16(acc, wp[c * 540], xrT + c * 16);
    float bv = bt[o];
#pragma unroll
    for (int j = 0; j < 16; j++)
      qkvb[(row0 + j) * 540 + o] = __float2bfloat16(acc[j] + bv);
  }
}

// ---------------- attention per (window, head) ----------------

__global__ __launch_bounds__(256) void k_attn(const bf16* __restrict__ qkvb,
                                              const float* __restrict__ btab,
                                              const int* __restrict__ rpi,
                                              bf16* __restrict__ attn_o) {
  __shared__ float qkvh[90 * 65];  // [r][t], r: 0-29 q(d), 30-59 k(d), 60-89 v(d)
  __shared__ float sT[64 * 65];    // [m][n]
  int h = blockIdx.y;
  int bid = blockIdx.x;  // 4096 windows
  int b = bid >> 10, rem = bid & 1023, wi = rem >> 5, wj = rem & 31;
  long ibase = (long)b * 65536;
  // stage this window's head-h q,k,v
  for (int idx = threadIdx.x; idx < 64 * 90; idx += 256) {
    int t = idx / 90, r = idx % 90;
    long g = ibase + (wi * 8 + (t >> 3)) * IMG + wj * 8 + (t & 7);
    qkvh[r * 65 + t] = __bfloat162float(qkvb[g * 540 + h * 90 + r]);
  }
  __syncthreads();
  // scores: s[n][m] = q[n]·k[m] + bias[h][n][m], stored sT[m*65+n]
  {
    int m = threadIdx.x & 63, ng = threadIdx.x >> 6;
    int n0 = ng * 16;
    float acc[16];
#pragma unroll
    for (int j = 0; j < 16; j++) acc[j] = 0.f;
    for (int d = 0; d < 30; d++) {
      float kv = qkvh[(30 + d) * 65 + m];
      const float* qp = qkvh + d * 65 + n0;
#pragma unroll
      for (int j = 0; j < 16; j++) acc[j] += kv * qp[j];
    }
#pragma unroll
    for (int j = 0; j < 16; j++) {
      int n = n0 + j;
      sT[m * 65 + n] = acc[j] + btab[rpi[n * 64 + m] * 6 + h];
    }
  }
  __syncthreads();
  // softmax over m per query n
  if (threadIdx.x < 64) {
    int n = threadIdx.x;
    float mx = -1e30f;
    for (int m2 = 0; m2 < 64; m2++) mx = fmaxf(mx, sT[m2 * 65 + n]);
    float s = 0.f;
    for (int m2 = 0; m2 < 64; m2++) {
      float e = __expf(sT[m2 * 65 + n] - mx);
      sT[m2 * 65 + n] = e;
      s += e;
    }
    float inv = 1.f / s;
    for (int m2 = 0; m2 < 64; m2++) sT[m2 * 65 + n] *= inv;
  }
  __syncthreads();
  // PV: out[n][h*30+d] = sum_m p[n][m] * v[m][d]
  for (int it = threadIdx.x; it < 120; it += 256) {
    int d = it % 30, ng = it / 30;
    int n0 = ng * 16;
    float acc[16];
#pragma unroll
    for (int j = 0; j < 16; j++) acc[j] = 0.f;
    for (int m2 = 0; m2 < 64; m2++) {
      float vv = qkvh[(60 + d) * 65 + m2];
      const float* pp = sT + m2 * 65 + n0;
#pragma unroll
      for (int j = 0; j < 16; j++) acc[j] += vv * pp[j];
    }
#pragma unroll
    for (int j = 0; j < 16; j++) {
      int n = n0 + j;
      long g = ibase + (wi * 8 + (n >> 3)) * IMG + wj * 8 + (n & 7);
      attn_o[g * 180 + h * 30 + d] = __float2bfloat16(acc[j]);
    }
  }
}

// ---------------- proj GEMM + residual combine -> xmid (d_out) ----------------

__global__ __launch_bounds__(256) void k_proj(const bf16* __restrict__ attn_o,
                                              const float* __restrict__ wt,
                                              const float* __restrict__ pb,
                                              const float* __restrict__ x0,
                                              const bf16* __restrict__ y180,
                                              const float* __restrict__ a_se,
                                              float* __restrict__ xmid) {
  __shared__ float xrT[180 * 16];
  long row0 = (long)blockIdx.x * 16;
  for (int idx = threadIdx.x; idx < 16 * 180; idx += 256) {
    int r = idx / 180, c = idx % 180;
    xrT[c * 16 + r] = __bfloat162float(attn_o[(row0 + r) * 180 + c]);
  }
  __syncthreads();
  for (int o = threadIdx.x; o < 180; o += 256) {
    float acc[16];
#pragma unroll
    for (int j = 0; j < 16; j++) acc[j] = 0.f;
    const float* wp = wt + o;
    for (int c = 0; c < 180; c++) fma16(acc, wp[c * 180], xrT + c * 16);
    float bv = pb[o];
#pragma unroll
    for (int j = 0; j < 16; j++) {
      long g = row0 + j;
      int b = (int)(g >> 16);
      long gi = g * 180 + o;
      xmid[gi] = x0[gi] + acc[j] + bv +
                 __bfloat162float(y180[gi]) * a_se[b * 180 + o] * 0.01f;
    }
  }
}

// ---------------- fused LN2 + FC1 + GELU + FC2 + residual ----------------

__global__ __launch_bounds__(256) void k_mlp(float* __restrict__ xio,
                                             const float* __restrict__ gw,
                                             const float* __restrict__ bw,
                                             const float* __restrict__ fc1T,
                                             const float* __restrict__ fc1b,
                                             const float* __restrict__ fc2T,
                                             const float* __restrict__ fc2b) {
  __shared__ float xrT[180 * 16];  // LN'd input, [c][r]
  __shared__ float hT[720 * 16];   // hidden, [o][r]
  int wv = threadIdx.x >> 6, lane = threadIdx.x & 63;
  long row0 = (long)blockIdx.x * 16;
  for (int rr = 0; rr < 4; rr++) {
    int r = wv * 4 + rr;
    const float* xr = xio + (row0 + r) * 180;
    float v0 = xr[lane], v1 = xr[lane + 64];
    float v2 = (lane < 52) ? xr[lane + 128] : 0.f;
    float s = wave_reduce_add(v0 + v1 + v2);
    float ss = wave_reduce_add(v0 * v0 + v1 * v1 + v2 * v2);
    float mean = s * (1.f / 180.f);
    float rstd = rsqrtf(ss * (1.f / 180.f) - mean * mean + 1e-5f);
    xrT[lane * 16 + r] = (v0 - mean) * rstd * gw[lane] + bw[lane];
    xrT[(lane + 64) * 16 + r] = (v1 - mean) * rstd * gw[lane + 64] + bw[lane + 64];
    if (lane < 52)
      xrT[(lane + 128) * 16 + r] = (v2 - mean) * rstd * gw[lane + 128] + bw[lane + 128];
  }
  __syncthreads();
  for (int o = threadIdx.x; o < 720; o += 256) {
    float acc[16];
#pragma unroll
    for (int j = 0; j < 16; j++) acc[j] = 0.f;
    const float* wp = fc1T + o;
    for (int c = 0; c < 180; c++) fma16(acc, wp[c * 720], xrT + c * 16);
    float bv = fc1b[o];
#pragma unroll
    for (int j = 0; j < 16; j++) hT[o * 16 + j] = gelu_f(acc[j] + bv);
  }
  __syncthreads();
  for (int o = threadIdx.x; o < 180; o += 256) {
    float acc[16];
#pragma unroll
    for (int j = 0; j < 16; j++) acc[j] = 0.f;
    const float* wp = fc2T + o;
    for (int c = 0; c < 720; c++) fma16(acc, wp[c * 180], hT + c * 16);
    float bv = fc2b[o];
#pragma unroll
    for (int j = 0; j < 16; j++) {
      long gi = (row0 + j) * 180 + o;
      xio[gi] += acc[j] + bv;
    }
  }
}

// ---------------- launch ----------------

extern "C" void kernel_launch(void* const* d_in, const int* in_sizes, int n_in,
                              void* d_out, int out_size, void* d_ws, size_t ws_size,
                              hipStream_t stream) {
  const float* x = (const float*)d_in[0];
  const float* ln1g = (const float*)d_in[1];
  const float* ln1b = (const float*)d_in[2];
  const float* qkvw = (const float*)d_in[3];
  const float* qkvbias = (const float*)d_in[4];
  const float* btab = (const float*)d_in[5];
  const float* projw = (const float*)d_in[6];
  const float* projb = (const float*)d_in[7];
  const float* cw1 = (const float*)d_in[8];
  const float* cb1 = (const float*)d_in[9];
  const float* cw2 = (const float*)d_in[10];
  const float* cb2 = (const float*)d_in[11];
  const float* caw1 = (const float*)d_in[12];
  const float* cab1 = (const float*)d_in[13];
  const float* caw2 = (const float*)d_in[14];
  const float* cab2 = (const float*)d_in[15];
  const float* ln2g = (const float*)d_in[16];
  const float* ln2b = (const float*)d_in[17];
  const float* fc1w = (const float*)d_in[18];
  const float* fc1b = (const float*)d_in[19];
  const float* fc2w = (const float*)d_in[20];
  const float* fc2b = (const float*)d_in[21];
  const int* rpi = (const int*)d_in[22];
  float* out = (float*)d_out;

  size_t off = 0;
  char* wsb = (char*)d_ws;
  auto alloc = [&](size_t bytes) -> char* {
    char* p = wsb + off;
    off = (off + bytes + 255) & ~(size_t)255;
    return p;
  };
  bf16* xn = (bf16*)alloc((size_t)N_TOK * 180 * 2);
  bf16* y60 = (bf16*)alloc((size_t)N_TOK * 60 * 2);
  bf16* y180 = (bf16*)alloc((size_t)N_TOK * 180 * 2);
  bf16* qkvb = (bf16*)alloc((size_t)N_TOK * 540 * 2);
  bf16* attn_o = (bf16*)alloc((size_t)N_TOK * 180 * 2);
  float* qkv_wt = (float*)alloc(540 * 180 * 4);
  float* qkv_bt = (float*)alloc(540 * 4);
  float* projT = (float*)alloc(180 * 180 * 4);
  float* fc1T = (float*)alloc(180 * 720 * 4);
  float* fc2T = (float*)alloc(720 * 180 * 4);
  float* w1r = (float*)alloc(9 * 180 * 60 * 4);
  float* w2r = (float*)alloc(9 * 60 * 180 * 4);
  float* chsum = (float*)alloc(720 * 4);
  float* a_se = (float*)alloc(720 * 4);
  if (off > ws_size) return;  // workspace too small: bail (bench will flag)

  k_zero<<<3, 256, 0, stream>>>(chsum, 720);
  k_repack_qkv<<<380, 256, 0, stream>>>(qkvw, qkvbias, qkv_wt, qkv_bt);
  k_repack_proj<<<127, 256, 0, stream>>>(projw, projT);
  k_repack_fc1<<<507, 256, 0, stream>>>(fc1w, fc1T);
  k_repack_fc2<<<507, 256, 0, stream>>>(fc2w, fc2T);
  k_repack_w1<<<380, 256, 0, stream>>>(cw1, w1r);
  k_repack_w2<<<380, 256, 0, stream>>>(cw2, w2r);

  k_ln1<<<65536, 256, 0, stream>>>(x, ln1g, ln1b, xn);
  k_conv1<<<dim3(256, 4), 256, 0, stream>>>(xn, w1r, cb1, y60);
  k_conv2<<<dim3(256, 2, 4), 256, 0, stream>>>(y60, w2r, cb2, y180);
  k_csum<<<dim3(256, 4), 192, 0, stream>>>(y180, chsum);
  k_se<<<4, 192, 0, stream>>>(chsum, caw1, cab1, caw2, cab2, a_se);
  k_qkv<<<16384, 256, 0, stream>>>(xn, qkv_wt, qkv_bt, qkvb);
  k_attn<<<dim3(4096, 6), 256, 0, stream>>>(qkvb, btab, rpi, attn_o);
  k_proj<<<16384, 256, 0, stream>>>(attn_o, projT, projb, x, y180, a_se, out);
  k_mlp<<<16384, 256, 0, stream>>>(out, ln2g, ln2b, fc1T, fc1b, fc2T, fc2b);
}

// Round 2
// 4240.802 us; speedup vs baseline: 1.6233x; 1.6233x over previous
//
#include <hip/hip_runtime.h>
#include <hip/hip_bf16.h>

typedef __hip_bfloat16 bf16;
typedef __attribute__((ext_vector_type(8))) short short8v;
typedef __attribute__((ext_vector_type(4))) float float4v;

#define N_TOK (4 * 65536)
#define IMG 256

__device__ __forceinline__ float wave_reduce_add(float v) {
#pragma unroll
  for (int m = 32; m > 0; m >>= 1) v += __shfl_xor(v, m, 64);
  return v;
}

__device__ __forceinline__ float gelu_f(float v) {
  return 0.5f * v * (1.f + erff(v * 0.70710678118654752f));
}

// fragment-linear activation layout: [t=row/64][ch=k/8][r=row%64][j=k%8]
__device__ __forceinline__ size_t frag_idx(long row, int k) {
  return ((((row >> 6) * 24) + (k >> 3)) << 9) + ((long)(row & 63) << 3) + (k & 7);
}

// ---------------- small utility / pack kernels ----------------

__global__ void k_zero(float* __restrict__ p, int n) {
  int i = blockIdx.x * 256 + threadIdx.x;
  if (i < n) p[i] = 0.f;
}

// qkv B pack: [nt 34][kb 6][lane 64][8], n-order: oo = h*90 + (mat*30 + d), q pre-scaled
__global__ void k_pack_qkv_b(const float* __restrict__ w, bf16* __restrict__ B) {
  int e = blockIdx.x * 256 + threadIdx.x;
  if (e >= 34 * 6 * 64) return;
  int lane = e & 63, kb = (e >> 6) % 6, nt = e / (6 * 64);
  int n = nt * 16 + (lane & 15);
  int kbase = kb * 32 + (lane >> 4) * 8;
  bf16* out = B + (size_t)e * 8;
#pragma unroll
  for (int j = 0; j < 8; j++) {
    int k = kbase + j;
    float v = 0.f;
    if (n < 540 && k < 180) {
      int hh = n / 90, r = n % 90, mat = r / 30, d = r % 30;
      int o = mat * 180 + hh * 30 + d;
      float s = (mat == 0) ? 0.18257418583505537f : 1.f;
      v = w[o * 180 + k] * s;
    }
    out[j] = __float2bfloat16(v);
  }
}

__global__ void k_pack_qkv_bias(const float* __restrict__ b, float* __restrict__ bt) {
  int n = blockIdx.x * 256 + threadIdx.x;
  if (n >= 544) return;
  float v = 0.f;
  if (n < 540) {
    int hh = n / 90, r = n % 90, mat = r / 30, d = r % 30;
    int o = mat * 180 + hh * 30 + d;
    float s = (mat == 0) ? 0.18257418583505537f : 1.f;
    v = b[o] * s;
  }
  bt[n] = v;
}

// proj B pack: [nt 12][kb 6][lane][8]: B[k][n] = proj_w[n*180+k]
__global__ void k_pack_proj_b(const float* __restrict__ w, bf16* __restrict__ B) {
  int e = blockIdx.x * 256 + threadIdx.x;
  if (e >= 12 * 6 * 64) return;
  int lane = e & 63, kb = (e >> 6) % 6, nt = e / (6 * 64);
  int n = nt * 16 + (lane & 15);
  int kbase = kb * 32 + (lane >> 4) * 8;
  bf16* out = B + (size_t)e * 8;
#pragma unroll
  for (int j = 0; j < 8; j++) {
    int k = kbase + j;
    out[j] = __float2bfloat16((n < 180 && k < 180) ? w[n * 180 + k] : 0.f);
  }
}

// fc1 B pack: [nt 46][kb 6][lane][8]: B[k][n] = fc1_w[n*180+k]
__global__ void k_pack_fc1_b(const float* __restrict__ w, bf16* __restrict__ B) {
  int e = blockIdx.x * 256 + threadIdx.x;
  if (e >= 46 * 6 * 64) return;
  int lane = e & 63, kb = (e >> 6) % 6, nt = e / (6 * 64);
  int n = nt * 16 + (lane & 15);
  int kbase = kb * 32 + (lane >> 4) * 8;
  bf16* out = B + (size_t)e * 8;
#pragma unroll
  for (int j = 0; j < 8; j++) {
    int k = kbase + j;
    out[j] = __float2bfloat16((n < 720 && k < 180) ? w[n * 180 + k] : 0.f);
  }
}

__global__ void k_pack_fc1_bias(const float* __restrict__ b, float* __restrict__ bt) {
  int n = blockIdx.x * 256 + threadIdx.x;
  if (n >= 736) return;
  bt[n] = (n < 720) ? b[n] : 0.f;
}

// fc2 B pack: [nt 12][kb 23][lane][8]: B[k][n] = fc2_w[n*720+k]
__global__ void k_pack_fc2_b(const float* __restrict__ w, bf16* __restrict__ B) {
  int e = blockIdx.x * 256 + threadIdx.x;
  if (e >= 12 * 23 * 64) return;
  int lane = e & 63, kb = (e >> 6) % 23, nt = e / (23 * 64);
  int n = nt * 16 + (lane & 15);
  int kbase = kb * 32 + (lane >> 4) * 8;
  bf16* out = B + (size_t)e * 8;
#pragma unroll
  for (int j = 0; j < 8; j++) {
    int k = kbase + j;
    out[j] = __float2bfloat16((n < 180 && k < 720) ? w[n * 720 + k] : 0.f);
  }
}

// conv weight repacks (fp32, as round 1)
__global__ void k_repack_w1(const float* __restrict__ w, float* __restrict__ wt) {
  int i = blockIdx.x * 256 + threadIdx.x;
  if (i >= 9 * 180 * 60) return;
  int o = i % 60; int t = i / 60; int c = t % 180; int kk = t / 180;
  int ky = kk / 3, kx = kk % 3;
  wt[i] = w[((o * 180 + c) * 3 + ky) * 3 + kx];
}

__global__ void k_repack_w2(const float* __restrict__ w, float* __restrict__ wt) {
  int i = blockIdx.x * 256 + threadIdx.x;
  if (i >= 9 * 60 * 180) return;
  int o = i % 180; int t = i / 180; int c = t % 60; int kk = t / 60;
  int ky = kk / 3, kx = kk % 3;
  wt[i] = w[((o * 60 + c) * 3 + ky) * 3 + kx];
}

// ---------------- LN1: x -> xn (frag layout, K padded to 192 w/ zeros) ----------------

__global__ __launch_bounds__(256) void k_ln1(const float* __restrict__ x,
                                             const float* __restrict__ gw,
                                             const float* __restrict__ bw,
                                             bf16* __restrict__ xnf) {
  int wv = threadIdx.x >> 6, lane = threadIdx.x & 63;
  long row = (long)blockIdx.x * 4 + wv;
  const float* xr = x + row * 180;
  float v0 = xr[lane];
  float v1 = xr[lane + 64];
  float v2 = (lane < 52) ? xr[lane + 128] : 0.f;
  float s = wave_reduce_add(v0 + v1 + v2);
  float ss = wave_reduce_add(v0 * v0 + v1 * v1 + v2 * v2);
  float mean = s * (1.f / 180.f);
  float rstd = rsqrtf(ss * (1.f / 180.f) - mean * mean + 1e-5f);
  bf16* base = xnf + (((row >> 6) * 24) << 9) + ((long)(row & 63) << 3);
  int ch = lane >> 3, j = lane & 7;
  base[((size_t)ch << 9) + j] =
      __float2bfloat16((v0 - mean) * rstd * gw[lane] + bw[lane]);
  base[((size_t)(ch + 8) << 9) + j] =
      __float2bfloat16((v1 - mean) * rstd * gw[lane + 64] + bw[lane + 64]);
  float v3 = (lane < 52) ? ((v2 - mean) * rstd * gw[lane + 128] + bw[lane + 128]) : 0.f;
  base[((size_t)(ch + 16) << 9) + j] = __float2bfloat16(v3);
}

// ---------------- conv1 3x3 180->60 + GELU (reads frag layout) ----------------

__global__ __launch_bounds__(256) void k_conv1(const bf16* __restrict__ xnf,
                                               const float* __restrict__ w1r,
                                               const float* __restrict__ b1,
                                               bf16* __restrict__ y60) {
  __shared__ float tile[18 * 18 * 36];
  int b = blockIdx.y;
  int ty = blockIdx.x >> 4, tx = blockIdx.x & 15;
  int px = threadIdx.x & 15, py = threadIdx.x >> 4;
  float acc[60];
#pragma unroll
  for (int o = 0; o < 60; o++) acc[o] = b1[o];
  long ibase = (long)b * 65536;
  for (int cc = 0; cc < 180; cc += 36) {
    __syncthreads();
    for (int idx = threadIdx.x; idx < 18 * 18 * 36; idx += 256) {
      int c = idx % 36; int t2 = idx / 36; int col = t2 % 18; int r = t2 / 18;
      int iy = ty * 16 - 1 + r, ix = tx * 16 - 1 + col;
      float v = 0.f;
      if (iy >= 0 && iy < IMG && ix >= 0 && ix < IMG)
        v = __bfloat162float(xnf[frag_idx(ibase + iy * IMG + ix, cc + c)]);
      tile[idx] = v;
    }
    __syncthreads();
    for (int kk = 0; kk < 9; kk++) {
      const float* wp = w1r + (kk * 180 + cc) * 60;
      const float* tp = tile + ((py + kk / 3) * 18 + (px + kk % 3)) * 36;
      for (int c = 0; c < 36; c++) {
        float v = tp[c];
        const float* w = wp + c * 60;
#pragma unroll
        for (int o = 0; o < 60; o++) acc[o] += v * w[o];
      }
    }
  }
  long g = ibase + (ty * 16 + py) * IMG + (tx * 16 + px);
  bf16* outp = y60 + g * 60;
#pragma unroll
  for (int o = 0; o < 60; o++) outp[o] = __float2bfloat16(gelu_f(acc[o]));
}

// ---------------- conv2 3x3 60->180 ----------------

__global__ __launch_bounds__(256) void k_conv2(const bf16* __restrict__ y60,
                                               const float* __restrict__ w2r,
                                               const float* __restrict__ b2,
                                               bf16* __restrict__ y180) {
  __shared__ float tile[18 * 18 * 30];
  int b = blockIdx.z, og = blockIdx.y;
  int ty = blockIdx.x >> 4, tx = blockIdx.x & 15;
  int px = threadIdx.x & 15, py = threadIdx.x >> 4;
  float acc[90];
  const float* bb = b2 + og * 90;
#pragma unroll
  for (int j = 0; j < 90; j++) acc[j] = bb[j];
  long ibase = (long)b * 65536;
  for (int cc = 0; cc < 60; cc += 30) {
    __syncthreads();
    for (int idx = threadIdx.x; idx < 18 * 18 * 30; idx += 256) {
      int c = idx % 30; int t2 = idx / 30; int col = t2 % 18; int r = t2 / 18;
      int iy = ty * 16 - 1 + r, ix = tx * 16 - 1 + col;
      float v = 0.f;
      if (iy >= 0 && iy < IMG && ix >= 0 && ix < IMG)
        v = __bfloat162float(y60[(ibase + iy * IMG + ix) * 60 + cc + c]);
      tile[idx] = v;
    }
    __syncthreads();
    for (int kk = 0; kk < 9; kk++) {
      const float* wp = w2r + (kk * 60 + cc) * 180 + og * 90;
      const float* tp = tile + ((py + kk / 3) * 18 + (px + kk % 3)) * 30;
      for (int c = 0; c < 30; c++) {
        float v = tp[c];
        const float* w = wp + c * 180;
#pragma unroll
        for (int j = 0; j < 90; j++) acc[j] += v * w[j];
      }
    }
  }
  long g = ibase + (ty * 16 + py) * IMG + (tx * 16 + px);
  bf16* outp = y180 + g * 180 + og * 90;
#pragma unroll
  for (int j = 0; j < 90; j++) outp[j] = __float2bfloat16(acc[j]);
}

// ---------------- per-channel sums + SE ----------------

__global__ __launch_bounds__(192) void k_csum(const bf16* __restrict__ y180,
                                              float* __restrict__ cs) {
  int c = threadIdx.x;
  if (c >= 180) return;
  int b = blockIdx.y;
  long base = ((long)b * 65536 + blockIdx.x * 256) * 180;
  float s = 0.f;
  for (int p = 0; p < 256; p++) s += __bfloat162float(y180[base + p * 180 + c]);
  atomicAdd(&cs[b * 180 + c], s);
}

__global__ __launch_bounds__(192) void k_se(const float* __restrict__ cs,
                                            const float* __restrict__ w1,
                                            const float* __restrict__ b1,
                                            const float* __restrict__ w2,
                                            const float* __restrict__ b2,
                                            float* __restrict__ a_se) {
  __shared__ float m[180];
  __shared__ float hid[6];
  int b = blockIdx.x, t = threadIdx.x;
  if (t < 180) m[t] = cs[b * 180 + t] * (1.f / 65536.f);
  __syncthreads();
  if (t < 6) {
    float s = b1[t];
    for (int c = 0; c < 180; c++) s += m[c] * w1[t * 180 + c];
    hid[t] = fmaxf(s, 0.f);
  }
  __syncthreads();
  if (t < 180) {
    float s = b2[t];
#pragma unroll
    for (int j = 0; j < 6; j++) s += hid[j] * w2[t * 6 + j];
    a_se[b * 180 + t] = 1.f / (1.f + __expf(-s));
  }
}

// ---------------- qkv GEMM via MFMA: 64 rows/block, N=544, K=192 ----------------

__global__ __launch_bounds__(256) void k_qkv_mfma(const bf16* __restrict__ xnf,
                                                  const bf16* __restrict__ Bq,
                                                  const float* __restrict__ btq,
                                                  bf16* __restrict__ qkvb) {
  __shared__ bf16 As[24 * 64 * 8];  // 24 KB, frag-linear
  int tid = threadIdx.x;
  const uint4* src = (const uint4*)(xnf + (size_t)blockIdx.x * 12288);
  uint4* dst = (uint4*)As;
#pragma unroll
  for (int it = 0; it < 6; it++) dst[it * 256 + tid] = src[it * 256 + tid];
  __syncthreads();
  int lane = tid & 63, wv = tid >> 6;
  int m = lane & 15, q = lane >> 4;
  long row0 = (long)blockIdx.x * 64 + wv * 16;
  const short8v* Ap = (const short8v*)As;
  const short8v* Bp = (const short8v*)Bq;
  for (int nt = 0; nt < 34; nt += 2) {
    float4v acc0 = {0.f, 0.f, 0.f, 0.f}, acc1 = {0.f, 0.f, 0.f, 0.f};
#pragma unroll
    for (int kb = 0; kb < 6; kb++) {
      short8v a = Ap[(kb * 4 + q) * 64 + wv * 16 + m];
      short8v b0 = Bp[(nt * 6 + kb) * 64 + lane];
      short8v b1 = Bp[((nt + 1) * 6 + kb) * 64 + lane];
      acc0 = __builtin_amdgcn_mfma_f32_16x16x32_bf16(a, b0, acc0, 0, 0, 0);
      acc1 = __builtin_amdgcn_mfma_f32_16x16x32_bf16(a, b1, acc1, 0, 0, 0);
    }
    int n0 = nt * 16 + m, n1 = n0 + 16;
    float bb0 = btq[n0], bb1 = btq[n1];
#pragma unroll
    for (int reg = 0; reg < 4; reg++) {
      long rw = row0 + q * 4 + reg;
      qkvb[rw * 544 + n0] = __float2bfloat16(acc0[reg] + bb0);
      qkvb[rw * 544 + n1] = __float2bfloat16(acc1[reg] + bb1);
    }
  }
}

// ---------------- attention per (window, head); writes frag layout ----------------

__global__ __launch_bounds__(256) void k_attn(const bf16* __restrict__ qkvb,
                                              const float* __restrict__ btab,
                                              const int* __restrict__ rpi,
                                              bf16* __restrict__ attnf) {
  __shared__ float qkvh[90 * 65];
  __shared__ float sT[64 * 65];
  int h = blockIdx.y;
  int bid = blockIdx.x;
  int b = bid >> 10, rem = bid & 1023, wi = rem >> 5, wj = rem & 31;
  long ibase = (long)b * 65536;
  // zero k-pad (180..191) once per token, by head-0 blocks
  if (h == 0 && threadIdx.x < 64) {
    int n = threadIdx.x;
    long g = ibase + (wi * 8 + (n >> 3)) * IMG + wj * 8 + (n & 7);
    bf16* bp = attnf + (((g >> 6) * 24) << 9) + ((long)(g & 63) << 3);
    *(uint2*)(bp + (22 << 9) + 4) = make_uint2(0u, 0u);
    *(uint4*)(bp + (23 << 9)) = make_uint4(0u, 0u, 0u, 0u);
  }
  for (int idx = threadIdx.x; idx < 64 * 90; idx += 256) {
    int t = idx / 90, r = idx % 90;
    long g = ibase + (wi * 8 + (t >> 3)) * IMG + wj * 8 + (t & 7);
    qkvh[r * 65 + t] = __bfloat162float(qkvb[g * 544 + h * 90 + r]);
  }
  __syncthreads();
  {
    int m = threadIdx.x & 63, ng = threadIdx.x >> 6;
    int n0 = ng * 16;
    float acc[16];
#pragma unroll
    for (int j = 0; j < 16; j++) acc[j] = 0.f;
    for (int d = 0; d < 30; d++) {
      float kv = qkvh[(30 + d) * 65 + m];
      const float* qp = qkvh + d * 65 + n0;
#pragma unroll
      for (int j = 0; j < 16; j++) acc[j] += kv * qp[j];
    }
#pragma unroll
    for (int j = 0; j < 16; j++) {
      int n = n0 + j;
      sT[m * 65 + n] = acc[j] + btab[rpi[n * 64 + m] * 6 + h];
    }
  }
  __syncthreads();
  if (threadIdx.x < 64) {
    int n = threadIdx.x;
    float mx = -1e30f;
    for (int m2 = 0; m2 < 64; m2++) mx = fmaxf(mx, sT[m2 * 65 + n]);
    float s = 0.f;
    for (int m2 = 0; m2 < 64; m2++) {
      float e = __expf(sT[m2 * 65 + n] - mx);
      sT[m2 * 65 + n] = e;
      s += e;
    }
    float inv = 1.f / s;
    for (int m2 = 0; m2 < 64; m2++) sT[m2 * 65 + n] *= inv;
  }
  __syncthreads();
  for (int it = threadIdx.x; it < 120; it += 256) {
    int d = it % 30, ng = it / 30;
    int n0 = ng * 16;
    float acc[16];
#pragma unroll
    for (int j = 0; j < 16; j++) acc[j] = 0.f;
    for (int m2 = 0; m2 < 64; m2++) {
      float vv = qkvh[(60 + d) * 65 + m2];
      const float* pp = sT + m2 * 65 + n0;
#pragma unroll
      for (int j = 0; j < 16; j++) acc[j] += vv * pp[j];
    }
    int k = h * 30 + d;
#pragma unroll
    for (int j = 0; j < 16; j++) {
      int n = n0 + j;
      long g = ibase + (wi * 8 + (n >> 3)) * IMG + wj * 8 + (n & 7);
      attnf[frag_idx(g, k)] = __float2bfloat16(acc[j]);
    }
  }
}

// ---------------- proj via MFMA + residual combine -> out (fp32) ----------------

__global__ __launch_bounds__(256) void k_proj_mfma(const bf16* __restrict__ attnf,
                                                   const bf16* __restrict__ Bp_,
                                                   const float* __restrict__ pb,
                                                   const float* __restrict__ x0,
                                                   const bf16* __restrict__ y180,
                                                   const float* __restrict__ a_se,
                                                   float* __restrict__ out) {
  __shared__ bf16 As[24 * 64 * 8];
  int tid = threadIdx.x;
  const uint4* src = (const uint4*)(attnf + (size_t)blockIdx.x * 12288);
  uint4* dst = (uint4*)As;
#pragma unroll
  for (int it = 0; it < 6; it++) dst[it * 256 + tid] = src[it * 256 + tid];
  __syncthreads();
  int lane = tid & 63, wv = tid >> 6;
  int m = lane & 15, q = lane >> 4;
  long row0 = (long)blockIdx.x * 64 + wv * 16;
  const short8v* Ap = (const short8v*)As;
  const short8v* Bpp = (const short8v*)Bp_;
  for (int nt = 0; nt < 12; nt += 2) {
    float4v acc0 = {0.f, 0.f, 0.f, 0.f}, acc1 = {0.f, 0.f, 0.f, 0.f};
#pragma unroll
    for (int kb = 0; kb < 6; kb++) {
      short8v a = Ap[(kb * 4 + q) * 64 + wv * 16 + m];
      short8v b0 = Bpp[(nt * 6 + kb) * 64 + lane];
      short8v b1 = Bpp[((nt + 1) * 6 + kb) * 64 + lane];
      acc0 = __builtin_amdgcn_mfma_f32_16x16x32_bf16(a, b0, acc0, 0, 0, 0);
      acc1 = __builtin_amdgcn_mfma_f32_16x16x32_bf16(a, b1, acc1, 0, 0, 0);
    }
    int n0 = nt * 16 + m, n1 = n0 + 16;
    float pb0 = pb[n0];
    float pb1 = (n1 < 180) ? pb[n1] : 0.f;
#pragma unroll
    for (int reg = 0; reg < 4; reg++) {
      long rw = row0 + q * 4 + reg;
      int bidx = (int)(rw >> 16);
      long gi0 = rw * 180 + n0;
      out[gi0] = x0[gi0] + acc0[reg] + pb0 +
                 __bfloat162float(y180[gi0]) * a_se[bidx * 180 + n0] * 0.01f;
      if (n1 < 180) {
        long gi1 = rw * 180 + n1;
        out[gi1] = x0[gi1] + acc1[reg] + pb1 +
                   __bfloat162float(y180[gi1]) * a_se[bidx * 180 + n1] * 0.01f;
      }
    }
  }
}

// ---------------- fused LN2 + FC1(GELU) + FC2 + residual, all MFMA ----------------

__global__ __launch_bounds__(256) void k_mlp_mfma(float* __restrict__ xio,
                                                  const float* __restrict__ gw,
                                                  const float* __restrict__ bw,
                                                  const bf16* __restrict__ B1,
                                                  const float* __restrict__ b1t,
                                                  const bf16* __restrict__ B2,
                                                  const float* __restrict__ fc2b) {
  __shared__ bf16 Axs[32 * 200];  // LN'd rows, row-major, stride 200
  __shared__ bf16 Hs[32 * 744];   // hidden, row-major, stride 744
  int tid = threadIdx.x, lane = tid & 63, wv = tid >> 6;
  long row0 = (long)blockIdx.x * 32;
  // LN2
  for (int rr = 0; rr < 8; rr++) {
    int r = wv * 8 + rr;
    const float* xr = xio + (row0 + r) * 180;
    float v0 = xr[lane], v1 = xr[lane + 64];
    float v2 = (lane < 52) ? xr[lane + 128] : 0.f;
    float s = wave_reduce_add(v0 + v1 + v2);
    float ss = wave_reduce_add(v0 * v0 + v1 * v1 + v2 * v2);
    float mean = s * (1.f / 180.f);
    float rstd = rsqrtf(ss * (1.f / 180.f) - mean * mean + 1e-5f);
    bf16* ar = Axs + r * 200;
    ar[lane] = __float2bfloat16((v0 - mean) * rstd * gw[lane] + bw[lane]);
    ar[lane + 64] = __float2bfloat16((v1 - mean) * rstd * gw[lane + 64] + bw[lane + 64]);
    float v3 = (lane < 52) ? ((v2 - mean) * rstd * gw[lane + 128] + bw[lane + 128]) : 0.f;
    ar[lane + 128] = __float2bfloat16(v3);
  }
  __syncthreads();
  int m = lane & 15, q = lane >> 4, mh = wv & 1, ng = wv >> 1;
  int rA = mh * 16 + m;
  // FC1 + GELU -> Hs
  for (int i = 0; i < 23; i += 2) {
    int nt0 = ng * 23 + i;
    bool two = (i + 1) < 23;
    float4v acc0 = {0.f, 0.f, 0.f, 0.f}, acc1 = {0.f, 0.f, 0.f, 0.f};
#pragma unroll
    for (int kb = 0; kb < 6; kb++) {
      short8v a = *(const short8v*)(Axs + rA * 200 + kb * 32 + q * 8);
      short8v b0 = ((const short8v*)B1)[(nt0 * 6 + kb) * 64 + lane];
      acc0 = __builtin_amdgcn_mfma_f32_16x16x32_bf16(a, b0, acc0, 0, 0, 0);
      if (two) {
        short8v b1 = ((const short8v*)B1)[((nt0 + 1) * 6 + kb) * 64 + lane];
        acc1 = __builtin_amdgcn_mfma_f32_16x16x32_bf16(a, b1, acc1, 0, 0, 0);
      }
    }
    int n0 = nt0 * 16 + m;
    float bb0 = b1t[n0];
    float bb1 = two ? b1t[n0 + 16] : 0.f;
#pragma unroll
    for (int reg = 0; reg < 4; reg++) {
      int r = mh * 16 + q * 4 + reg;
      Hs[r * 744 + n0] = __float2bfloat16(gelu_f(acc0[reg] + bb0));
      if (two) Hs[r * 744 + n0 + 16] = __float2bfloat16(gelu_f(acc1[reg] + bb1));
    }
  }
  __syncthreads();
  // FC2 + residual
  for (int i = 0; i < 6; i += 2) {
    int nt0 = ng * 6 + i;
    float4v acc0 = {0.f, 0.f, 0.f, 0.f}, acc1 = {0.f, 0.f, 0.f, 0.f};
    for (int kb = 0; kb < 23; kb++) {
      short8v a = *(const short8v*)(Hs + rA * 744 + kb * 32 + q * 8);
      short8v b0 = ((const short8v*)B2)[(nt0 * 23 + kb) * 64 + lane];
      short8v b1 = ((const short8v*)B2)[((nt0 + 1) * 23 + kb) * 64 + lane];
      acc0 = __builtin_amdgcn_mfma_f32_16x16x32_bf16(a, b0, acc0, 0, 0, 0);
      acc1 = __builtin_amdgcn_mfma_f32_16x16x32_bf16(a, b1, acc1, 0, 0, 0);
    }
    int n0 = nt0 * 16 + m, n1 = n0 + 16;
#pragma unroll
    for (int reg = 0; reg < 4; reg++) {
      long rw = row0 + mh * 16 + q * 4 + reg;
      if (n0 < 180) xio[rw * 180 + n0] += acc0[reg] + fc2b[n0];
      if (n1 < 180) xio[rw * 180 + n1] += acc1[reg] + fc2b[n1];
    }
  }
}

// ---------------- launch ----------------

extern "C" void kernel_launch(void* const* d_in, const int* in_sizes, int n_in,
                              void* d_out, int out_size, void* d_ws, size_t ws_size,
                              hipStream_t stream) {
  const float* x = (const float*)d_in[0];
  const float* ln1g = (const float*)d_in[1];
  const float* ln1b = (const float*)d_in[2];
  const float* qkvw = (const float*)d_in[3];
  const float* qkvbias = (const float*)d_in[4];
  const float* btab = (const float*)d_in[5];
  const float* projw = (const float*)d_in[6];
  const float* projb = (const float*)d_in[7];
  const float* cw1 = (const float*)d_in[8];
  const float* cb1 = (const float*)d_in[9];
  const float* cw2 = (const float*)d_in[10];
  const float* cb2 = (const float*)d_in[11];
  const float* caw1 = (const float*)d_in[12];
  const float* cab1 = (const float*)d_in[13];
  const float* caw2 = (const float*)d_in[14];
  const float* cab2 = (const float*)d_in[15];
  const float* ln2g = (const float*)d_in[16];
  const float* ln2b = (const float*)d_in[17];
  const float* fc1w = (const float*)d_in[18];
  const float* fc1b = (const float*)d_in[19];
  const float* fc2w = (const float*)d_in[20];
  const float* fc2b = (const float*)d_in[21];
  const int* rpi = (const int*)d_in[22];
  float* out = (float*)d_out;

  size_t off = 0;
  char* wsb = (char*)d_ws;
  auto alloc = [&](size_t bytes) -> char* {
    char* p = wsb + off;
    off = (off + bytes + 255) & ~(size_t)255;
    return p;
  };
  bf16* xnf = (bf16*)alloc((size_t)N_TOK * 192 * 2);   // also reused as attnf
  bf16* y60 = (bf16*)alloc((size_t)N_TOK * 60 * 2);
  bf16* y180 = (bf16*)alloc((size_t)N_TOK * 180 * 2);
  bf16* qkvb = (bf16*)alloc((size_t)N_TOK * 544 * 2);
  bf16* Bq = (bf16*)alloc(34 * 6 * 64 * 8 * 2);
  float* btq = (float*)alloc(544 * 4);
  bf16* Bp = (bf16*)alloc(12 * 6 * 64 * 8 * 2);
  bf16* B1 = (bf16*)alloc(46 * 6 * 64 * 8 * 2);
  float* b1t = (float*)alloc(736 * 4);
  bf16* B2 = (bf16*)alloc(12 * 23 * 64 * 8 * 2);
  float* w1r = (float*)alloc(9 * 180 * 60 * 4);
  float* w2r = (float*)alloc(9 * 60 * 180 * 4);
  float* chsum = (float*)alloc(720 * 4);
  float* a_se = (float*)alloc(720 * 4);
  if (off > ws_size) return;
  bf16* attnf = xnf;  // xnf dead after k_qkv/k_conv1; reuse for attention output

  k_zero<<<3, 256, 0, stream>>>(chsum, 720);
  k_pack_qkv_b<<<51, 256, 0, stream>>>(qkvw, Bq);
  k_pack_qkv_bias<<<3, 256, 0, stream>>>(qkvbias, btq);
  k_pack_proj_b<<<18, 256, 0, stream>>>(projw, Bp);
  k_pack_fc1_b<<<69, 256, 0, stream>>>(fc1w, B1);
  k_pack_fc1_bias<<<3, 256, 0, stream>>>(fc1b, b1t);
  k_pack_fc2_b<<<69, 256, 0, stream>>>(fc2w, B2);
  k_repack_w1<<<380, 256, 0, stream>>>(cw1, w1r);
  k_repack_w2<<<380, 256, 0, stream>>>(cw2, w2r);

  k_ln1<<<65536, 256, 0, stream>>>(x, ln1g, ln1b, xnf);
  k_conv1<<<dim3(256, 4), 256, 0, stream>>>(xnf, w1r, cb1, y60);
  k_conv2<<<dim3(256, 2, 4), 256, 0, stream>>>(y60, w2r, cb2, y180);
  k_csum<<<dim3(256, 4), 192, 0, stream>>>(y180, chsum);
  k_se<<<4, 192, 0, stream>>>(chsum, caw1, cab1, caw2, cab2, a_se);
  k_qkv_mfma<<<4096, 256, 0, stream>>>(xnf, Bq, btq, qkvb);
  k_attn<<<dim3(4096, 6), 256, 0, stream>>>(qkvb, btab, rpi, attnf);
  k_proj_mfma<<<4096, 256, 0, stream>>>(attnf, Bp, projb, x, y180, a_se, out);
  k_mlp_mfma<<<8192, 256, 0, stream>>>(out, ln2g, ln2b, B1, b1t, B2, fc2b);
}